// Round 14
// baseline (218.228 us; speedup 1.0000x reference)
//
#include <hip/hip_runtime.h>
#include <hip/hip_bf16.h>

#define NN   100000
#define EE   1600000
#define DIN  128
#define HH   64
#define DEA  8
#define NCLS 2
#define BSZ  128                  // dst nodes per bucket
#define NBUCK ((NN + BSZ - 1) / BSZ)   // 782
#define CAPG 2368                 // per-bucket window capacity (mean 2046, sd ~45, +7 sigma)
#define CAP  4096                 // per-bucket LDS edge capacity
#define NCHUNK 100                // scatter blocks; EE/NCHUNK = 16000 edges each, exact
#define CHUNK (EE / NCHUNK)

typedef __hip_bfloat16 bf16;
typedef short  short8 __attribute__((ext_vector_type(8)));
typedef float  f32x4  __attribute__((ext_vector_type(4)));

__device__ __forceinline__ void bf2x(unsigned u, float& lo, float& hi) {
    union { unsigned i; float f; } a, b;
    a.i = u << 16; b.i = u & 0xffff0000u;
    lo = a.f; hi = b.f;
}
__device__ __forceinline__ short f2bs(float f) {
    unsigned u = __float_as_uint(f);
    return (short)((u + 0x7fffu + ((u >> 16) & 1u)) >> 16);
}
__device__ __forceinline__ short8 cvt8(float4 a, float4 b) {
    short8 r;
    r[0] = f2bs(a.x); r[1] = f2bs(a.y); r[2] = f2bs(a.z); r[3] = f2bs(a.w);
    r[4] = f2bs(b.x); r[5] = f2bs(b.y); r[6] = f2bs(b.z); r[7] = f2bs(b.w);
    return r;
}
__device__ __forceinline__ f32x4 z4() {
    f32x4 z; z[0] = 0.f; z[1] = 0.f; z[2] = 0.f; z[3] = 0.f; return z;
}

// ---------- K2 (MFMA): h = relu(x@W_enc+b); hg = h@W_gat; s_src/s_dst = hg . a ----------
#define WE_STRIDE 136
#define WG_STRIDE 72
#define TB_STRIDE 68
__global__ __launch_bounds__(256) void k_encode(
        const float* __restrict__ x,
        const float* __restrict__ W_enc, const float* __restrict__ b_enc,
        const float* __restrict__ W_gat,
        const float* __restrict__ a_src, const float* __restrict__ a_dst,
        bf16* __restrict__ hg_, float* __restrict__ s_src, float* __restrict__ s_dst) {
    __shared__ short wencT[64 * WE_STRIDE];
    __shared__ short wgatT[64 * WG_STRIDE];
    __shared__ float tb[4][16 * TB_STRIDE];
    short* hg = (short*)hg_;
    int tid = threadIdx.x;
    for (int i = tid; i < DIN * HH; i += 256) {
        int k = i >> 6, n = i & 63;
        wencT[n * WE_STRIDE + k] = f2bs(W_enc[i]);
    }
    for (int i = tid; i < HH * HH; i += 256) {
        int k = i >> 6, n = i & 63;
        wgatT[n * WG_STRIDE + k] = f2bs(W_gat[i]);
    }
    __syncthreads();
    int w = tid >> 6, l = tid & 63, m = l & 15, h = l >> 4;
    short8 wg[2][4];
    #pragma unroll
    for (int kt = 0; kt < 2; kt++)
        #pragma unroll
        for (int nt = 0; nt < 4; nt++)
            wg[kt][nt] = *(short8*)&wgatT[(nt * 16 + m) * WG_STRIDE + kt * 32 + h * 8];
    float avs[4], avd[4], ben[4];
    #pragma unroll
    for (int nt = 0; nt < 4; nt++) {
        avs[nt] = a_src[nt * 16 + m];
        avd[nt] = a_dst[nt * 16 + m];
        ben[nt] = b_enc[nt * 16 + m];
    }
    int tp = blockIdx.x * 4 + w;
    if (tp >= NN / 32) return;
    int n0 = tp * 32;
    float* tbw = tb[w];

    f32x4 acc1[2][4];
    #pragma unroll
    for (int rt = 0; rt < 2; rt++)
        #pragma unroll
        for (int nt = 0; nt < 4; nt++) acc1[rt][nt] = z4();
    #pragma unroll
    for (int kt = 0; kt < 4; kt++) {
        short8 af[2];
        #pragma unroll
        for (int rt = 0; rt < 2; rt++) {
            const float* xp = &x[(size_t)(n0 + rt * 16 + m) * DIN + kt * 32 + h * 8];
            af[rt] = cvt8(*(const float4*)xp, *(const float4*)(xp + 4));
        }
        #pragma unroll
        for (int nt = 0; nt < 4; nt++) {
            short8 bf = *(short8*)&wencT[(nt * 16 + m) * WE_STRIDE + kt * 32 + h * 8];
            acc1[0][nt] = __builtin_amdgcn_mfma_f32_16x16x32_bf16(af[0], bf, acc1[0][nt], 0, 0, 0);
            acc1[1][nt] = __builtin_amdgcn_mfma_f32_16x16x32_bf16(af[1], bf, acc1[1][nt], 0, 0, 0);
        }
    }
    #pragma unroll
    for (int rt = 0; rt < 2; rt++) {
        #pragma unroll
        for (int nt = 0; nt < 4; nt++)
            #pragma unroll
            for (int r = 0; r < 4; r++) {
                float hv = fmaxf(acc1[rt][nt][r] + ben[nt], 0.f);
                tbw[(h * 4 + r) * TB_STRIDE + nt * 16 + m] = hv;
            }
        f32x4 acc2[4];
        #pragma unroll
        for (int nt = 0; nt < 4; nt++) acc2[nt] = z4();
        #pragma unroll
        for (int kt = 0; kt < 2; kt++) {
            const float* tp_ = &tbw[m * TB_STRIDE + kt * 32 + h * 8];
            short8 af2 = cvt8(*(const float4*)tp_, *(const float4*)(tp_ + 4));
            #pragma unroll
            for (int nt = 0; nt < 4; nt++)
                acc2[nt] = __builtin_amdgcn_mfma_f32_16x16x32_bf16(af2, wg[kt][nt], acc2[nt], 0, 0, 0);
        }
        float ps[4] = {0.f, 0.f, 0.f, 0.f}, pd[4] = {0.f, 0.f, 0.f, 0.f};
        #pragma unroll
        for (int nt = 0; nt < 4; nt++)
            #pragma unroll
            for (int r = 0; r < 4; r++) {
                float v = acc2[nt][r];
                ps[r] = fmaf(v, avs[nt], ps[r]);
                pd[r] = fmaf(v, avd[nt], pd[r]);
                hg[(size_t)(n0 + rt * 16 + h * 4 + r) * HH + nt * 16 + m] = f2bs(v);
            }
        #pragma unroll
        for (int off = 1; off < 16; off <<= 1)
            #pragma unroll
            for (int r = 0; r < 4; r++) {
                ps[r] += __shfl_xor(ps[r], off);
                pd[r] += __shfl_xor(pd[r], off);
            }
        if (m == 0) {
            *(float4*)&s_src[n0 + rt * 16 + h * 4] = make_float4(ps[0], ps[1], ps[2], ps[3]);
            *(float4*)&s_dst[n0 + rt * 16 + h * 4] = make_float4(pd[0], pd[1], pd[2], pd[3]);
        }
    }
}

// ---------- K-cvt: attr f32 -> bf16, full-GPU streaming ----------
__global__ __launch_bounds__(256) void k_cvt(const float* __restrict__ attr,
                                             short* __restrict__ attr16) {
    int i = blockIdx.x * blockDim.x + threadIdx.x;
    int stride = gridDim.x * blockDim.x;
    for (int j = i; j < EE * DEA / 8; j += stride) {
        const float4* p = (const float4*)(attr + (size_t)j * 8);
        *(short8*)(attr16 + (size_t)j * 8) = cvt8(p[0], p[1]);
    }
}

// ---------- B3': two-level scatter (pure), 1024 thr/block, 100 blocks ----------
__global__ __launch_bounds__(1024) void k_cscatter(
        const int* __restrict__ src, const int* __restrict__ dst,
        int* bcur, unsigned* __restrict__ ebuf) {
    __shared__ int cnt[NBUCK];
    __shared__ int cur[NBUCK];
    int tid = threadIdx.x;
    int e0 = blockIdx.x * CHUNK;
    for (int i = tid; i < NBUCK; i += 1024) cnt[i] = 0;
    __syncthreads();
    for (int i = tid; i < CHUNK; i += 1024)
        atomicAdd(&cnt[dst[e0 + i] >> 7], 1);          // BSZ = 128
    __syncthreads();
    for (int i = tid; i < NBUCK; i += 1024) {
        int c = cnt[i];
        int base = c ? atomicAdd(&bcur[i], c) : 0;     // reserve range in bucket window
        cur[i] = i * CAPG + base;
    }
    __syncthreads();
    for (int i = tid; i < CHUNK; i += 1024) {
        int dv = dst[e0 + i], sv = src[e0 + i];
        int b  = dv >> 7;
        int dl = dv & (BSZ - 1);
        int pos = atomicAdd(&cur[b], 1);
        ebuf[pos] = ((unsigned)dl << 24) | (unsigned)sv;
    }
}

// ---------- B4+K7 fused: per-bucket sort -> register agg -> LDS agg -> node-head MFMA ----
// Phases: (1) counting sort in LDS, (2) wave-per-node softmax+agg into aggL (bf16,
// stride-72 rows: MFMA-phase reads land 2-way on banks = free), (3) 12-MFMA head per
// 16-row tile: logits + p_src/p_dst. p_src is a SEPARATE buffer (fused phase-3 writes
// would race other blocks' phase-2 hg gathers if aliased).
#define WC_STRIDE 72
#define AGG_STRIDE 72
__global__ __launch_bounds__(512) void k_baggnode(
        const unsigned* __restrict__ ebuf, const int* __restrict__ bcur,
        const float* __restrict__ s_src, const float* __restrict__ s_dst,
        const bf16* __restrict__ hg,
        const float* __restrict__ Wn1, const float* __restrict__ bn1,
        const float* __restrict__ Wn2, const float* __restrict__ bn2,
        const float* __restrict__ We1,
        bf16* __restrict__ p_src_, bf16* __restrict__ p_dst_,
        float* __restrict__ out_node) {
    __shared__ short wcatT[192 * WC_STRIDE];   // 27648 B
    __shared__ short aggL[BSZ * AGG_STRIDE];   // 18432 B
    __shared__ unsigned sl[CAP];               // 16384 B
    __shared__ int cnt[BSZ], sstart[BSZ], spos[BSZ], sscan[BSZ];   // 2048 B
    short* p_src = (short*)p_src_;
    short* p_dst = (short*)p_dst_;
    int tid = threadIdx.x;
    int b = blockIdx.x;
    // stage concat weights [Wn1|We1s|We1d] transposed bf16
    for (int i = tid; i < 3 * HH * HH; i += 512) {
        int mat = i >> 12, j = i & 4095;
        int k = j >> 6, l2 = j & 63;
        float v = (mat == 0) ? Wn1[j] : (mat == 1 ? We1[j] : We1[HH * HH + j]);
        wcatT[(mat * 64 + l2) * WC_STRIDE + k] = f2bs(v);
    }
    int rs = b * CAPG;
    int ne = min(bcur[b], CAP);
    for (int i = tid; i < BSZ; i += 512) cnt[i] = 0;
    __syncthreads();
    // phase 1: counting sort
    for (int i = tid; i < ne; i += 512)
        atomicAdd(&cnt[ebuf[rs + i] >> 24], 1);
    __syncthreads();
    int v = (tid < BSZ) ? cnt[tid] : 0;
    if (tid < BSZ) sscan[tid] = v;
    __syncthreads();
    for (int s = 1; s < BSZ; s <<= 1) {
        int add = (tid < BSZ && tid >= s) ? sscan[tid - s] : 0;
        __syncthreads();
        if (tid < BSZ) sscan[tid] += add;
        __syncthreads();
    }
    if (tid < BSZ) { sstart[tid] = sscan[tid] - v; spos[tid] = sscan[tid] - v; }
    __syncthreads();
    for (int i = tid; i < ne; i += 512) {
        unsigned p = ebuf[rs + i];
        int dl = p >> 24;
        int q = atomicAdd(&spos[dl], 1);
        sl[q] = p & 0xFFFFFFu;
    }
    __syncthreads();
    // phase 2: wave-per-node softmax + agg (m=0 shift exact), result -> aggL bf16
    int lane = tid & 63, wv = tid >> 6;
    int lane8 = lane & 7, grp = lane >> 3;
    for (int dl = wv; dl < BSZ; dl += 8) {
        int node = b * BSZ + dl;
        if (node >= NN) break;
        int st = sstart[dl], deg = cnt[dl];
        float sd = s_dst[node];
        float a[8] = {0.f}, denom = 0.f;
        for (int i = grp; i < deg; i += 8) {
            int sv = sl[st + i];
            float s = s_src[sv] + sd;
            s = (s >= 0.f) ? s : 0.2f * s;    // leaky_relu 0.2
            float ex = __expf(s);
            denom += ex;
            uint4 u = *(const uint4*)&hg[(size_t)sv * HH + lane8 * 8];
            float f0, f1, f2, f3, f4, f5, f6, f7;
            bf2x(u.x, f0, f1); bf2x(u.y, f2, f3);
            bf2x(u.z, f4, f5); bf2x(u.w, f6, f7);
            a[0] = fmaf(ex, f0, a[0]); a[1] = fmaf(ex, f1, a[1]);
            a[2] = fmaf(ex, f2, a[2]); a[3] = fmaf(ex, f3, a[3]);
            a[4] = fmaf(ex, f4, a[4]); a[5] = fmaf(ex, f5, a[5]);
            a[6] = fmaf(ex, f6, a[6]); a[7] = fmaf(ex, f7, a[7]);
        }
        #pragma unroll
        for (int off = 8; off < 64; off <<= 1) {
            #pragma unroll
            for (int j = 0; j < 8; j++) a[j] += __shfl_xor(a[j], off);
            denom += __shfl_xor(denom, off);
        }
        if (lane < 8) {
            float inv = 1.f / (denom + 1e-9f);
            short8 r;
            #pragma unroll
            for (int j = 0; j < 8; j++) r[j] = f2bs(a[j] * inv);
            *(short8*)&aggL[dl * AGG_STRIDE + lane8 * 8] = r;
        }
    }
    __syncthreads();
    // phase 3: node-head MFMA. Wave w owns 16 local rows [w*16, w*16+16).
    int m = lane & 15, h = lane >> 4;
    int node16 = b * BSZ + wv * 16;
    if (node16 >= NN) return;       // NN % 16 == 0 -> tile-level guard suffices
    float ben[4], wn2a[4], wn2b[4];
    #pragma unroll
    for (int nt = 0; nt < 4; nt++) {
        ben[nt]  = bn1[nt * 16 + m];
        wn2a[nt] = Wn2[(nt * 16 + m) * NCLS + 0];
        wn2b[nt] = Wn2[(nt * 16 + m) * NCLS + 1];
    }
    float bn20 = bn2[0], bn21 = bn2[1];
    f32x4 acc[12];
    #pragma unroll
    for (int nt = 0; nt < 12; nt++) acc[nt] = z4();
    #pragma unroll
    for (int kt = 0; kt < 2; kt++) {
        short8 av = *(const short8*)&aggL[(wv * 16 + m) * AGG_STRIDE + kt * 32 + h * 8];
        short8 af;
        #pragma unroll
        for (int j = 0; j < 8; j++) af[j] = (av[j] < 0) ? (short)0 : av[j];  // exact relu
        #pragma unroll
        for (int nt = 0; nt < 12; nt++) {
            short8 bf = *(short8*)&wcatT[(nt * 16 + m) * WC_STRIDE + kt * 32 + h * 8];
            acc[nt] = __builtin_amdgcn_mfma_f32_16x16x32_bf16(af, bf, acc[nt], 0, 0, 0);
        }
    }
    float l0[4] = {0.f, 0.f, 0.f, 0.f}, l1[4] = {0.f, 0.f, 0.f, 0.f};
    #pragma unroll
    for (int nt = 0; nt < 4; nt++)
        #pragma unroll
        for (int r = 0; r < 4; r++) {
            float t = fmaxf(acc[nt][r] + ben[nt], 0.f);
            l0[r] = fmaf(t, wn2a[nt], l0[r]);
            l1[r] = fmaf(t, wn2b[nt], l1[r]);
        }
    #pragma unroll
    for (int nt = 0; nt < 4; nt++)
        #pragma unroll
        for (int r = 0; r < 4; r++) {
            size_t row = (size_t)(node16 + h * 4 + r) * HH + nt * 16 + m;
            p_src[row] = f2bs(acc[nt + 4][r]);
            p_dst[row] = f2bs(acc[nt + 8][r]);
        }
    #pragma unroll
    for (int off = 1; off < 16; off <<= 1)
        #pragma unroll
        for (int r = 0; r < 4; r++) {
            l0[r] += __shfl_xor(l0[r], off);
            l1[r] += __shfl_xor(l1[r], off);
        }
    if (m == 0) {
        #pragma unroll
        for (int r = 0; r < 4; r++)
            *(float2*)&out_node[(size_t)(node16 + h * 4 + r) * NCLS] =
                make_float2(l0[r] + bn20, l1[r] + bn21);
    }
}

// ---------- K8: edge head. 16 lanes per 4-edge group; A16 selects bf16 attr stream. ----
template<bool A16>
__global__ __launch_bounds__(256) void k_edgehead(
        const int* __restrict__ src, const int* __restrict__ dst,
        const float* __restrict__ edge_attr, const short* __restrict__ attr16,
        const bf16* __restrict__ p_src, const bf16* __restrict__ p_dst,
        const float* __restrict__ We1, const float* __restrict__ be1,
        const float* __restrict__ We2, const float* __restrict__ be2,
        float* __restrict__ out_edge) {
    int tid = threadIdx.x;
    int lane16 = tid & 15;
    int grp    = (tid & 63) >> 4;
    int wave   = tid >> 6;
    float w1a[DEA][4], w2c0[4], w2c1[4], b1v[4];
    #pragma unroll
    for (int d = 0; d < DEA; d++) {
        float4 v = *(const float4*)&We1[(2 * HH + d) * HH + lane16 * 4];
        w1a[d][0] = v.x; w1a[d][1] = v.y; w1a[d][2] = v.z; w1a[d][3] = v.w;
    }
    float4 bv = *(const float4*)&be1[lane16 * 4];
    b1v[0] = bv.x; b1v[1] = bv.y; b1v[2] = bv.z; b1v[3] = bv.w;
    #pragma unroll
    for (int j = 0; j < 4; j++) {
        w2c0[j] = We2[(lane16 * 4 + j) * NCLS + 0];
        w2c1[j] = We2[(lane16 * 4 + j) * NCLS + 1];
    }
    float be20 = be2[0], be21 = be2[1];

    int stride = gridDim.x * 64;   // 64 edges per block-iteration; EE%64==0
    for (int e = blockIdx.x * 64 + wave * 16 + grp * 4; e < EE; e += stride) {
        int sv[4], dv[4];
        #pragma unroll
        for (int q = 0; q < 4; q++) { sv[q] = src[e + q]; dv[q] = dst[e + q]; }
        uint2 us[4], ud[4];
        uint4 ua[4];
        float4 at0[4], at1[4];
        #pragma unroll
        for (int q = 0; q < 4; q++) {
            us[q] = *(const uint2*)&p_src[(size_t)sv[q] * HH + lane16 * 4];
            ud[q] = *(const uint2*)&p_dst[(size_t)dv[q] * HH + lane16 * 4];
            if constexpr (A16) {
                ua[q] = *(const uint4*)&attr16[(size_t)(e + q) * DEA];
            } else {
                at0[q] = *(const float4*)&edge_attr[(size_t)(e + q) * DEA];
                at1[q] = *(const float4*)&edge_attr[(size_t)(e + q) * DEA + 4];
            }
        }
        float l0[4], l1[4];
        #pragma unroll
        for (int q = 0; q < 4; q++) {
            float s0, s1, s2, s3, d0, d1, d2, d3;
            bf2x(us[q].x, s0, s1); bf2x(us[q].y, s2, s3);
            bf2x(ud[q].x, d0, d1); bf2x(ud[q].y, d2, d3);
            float t[4] = {s0 + d0 + b1v[0], s1 + d1 + b1v[1],
                          s2 + d2 + b1v[2], s3 + d3 + b1v[3]};
            float av[DEA];
            if constexpr (A16) {
                bf2x(ua[q].x, av[0], av[1]); bf2x(ua[q].y, av[2], av[3]);
                bf2x(ua[q].z, av[4], av[5]); bf2x(ua[q].w, av[6], av[7]);
            } else {
                av[0] = at0[q].x; av[1] = at0[q].y; av[2] = at0[q].z; av[3] = at0[q].w;
                av[4] = at1[q].x; av[5] = at1[q].y; av[6] = at1[q].z; av[7] = at1[q].w;
            }
            l0[q] = 0.f; l1[q] = 0.f;
            #pragma unroll
            for (int j = 0; j < 4; j++) {
                #pragma unroll
                for (int d = 0; d < DEA; d++) t[j] = fmaf(av[d], w1a[d][j], t[j]);
                float r = fmaxf(t[j], 0.f);
                l0[q] = fmaf(r, w2c0[j], l0[q]);
                l1[q] = fmaf(r, w2c1[j], l1[q]);
            }
        }
        #pragma unroll
        for (int off = 8; off; off >>= 1)
            #pragma unroll
            for (int q = 0; q < 4; q++) {
                l0[q] += __shfl_xor(l0[q], off);
                l1[q] += __shfl_xor(l1[q], off);
            }
        if (lane16 == 0) {
            #pragma unroll
            for (int q = 0; q < 4; q++)
                *(float2*)&out_edge[(size_t)(e + q) * NCLS] =
                    make_float2(l0[q] + be20, l1[q] + be21);
        }
    }
}

extern "C" void kernel_launch(void* const* d_in, const int* in_sizes, int n_in,
                              void* d_out, int out_size, void* d_ws, size_t ws_size,
                              hipStream_t stream) {
    const float* x      = (const float*)d_in[0];
    const int*   ei     = (const int*)  d_in[1];
    const float* attr   = (const float*)d_in[2];
    const float* W_enc  = (const float*)d_in[3];
    const float* b_enc  = (const float*)d_in[4];
    const float* W_gat  = (const float*)d_in[5];
    const float* a_src  = (const float*)d_in[6];
    const float* a_dst  = (const float*)d_in[7];
    const float* Wn1    = (const float*)d_in[8];
    const float* bn1    = (const float*)d_in[9];
    const float* Wn2    = (const float*)d_in[10];
    const float* bn2    = (const float*)d_in[11];
    const float* We1    = (const float*)d_in[12];
    const float* be1    = (const float*)d_in[13];
    const float* We2    = (const float*)d_in[14];
    const float* be2    = (const float*)d_in[15];
    float* out = (float*)d_out;
    float* ws  = (float*)d_ws;

    // workspace layout (float units), need ~72.2 MB (same as R13, which fit):
    bf16*     hg      = (bf16*)ws;                        // [N*H] bf16
    bf16*     p_src   = (bf16*)(ws + (size_t)NN * 32);    // [N*H] bf16 (separate: fused-race)
    bf16*     p_dst   = (bf16*)(ws + (size_t)NN * 64);    // [N*H] bf16
    float*    ssrc    = ws + (size_t)NN * 96;             // [N]
    float*    sdst    = ssrc + NN;                        // [N]
    int*      bcur    = (int*)(sdst + NN);                // [NBUCK] count cursors
    unsigned* ebuf    = (unsigned*)(bcur + 1024);         // [NBUCK*CAPG] bucket windows
    short*    attr16  = (short*)(ebuf + (size_t)NBUCK * CAPG);  // [E*DEA] bf16 (optional)
    size_t    need    = (size_t)((char*)(attr16 + (size_t)EE * DEA) - (char*)ws);
    bool      a16     = ws_size >= need;                  // deterministic per-session

    const int* srcp = ei;
    const int* dstp = ei + EE;

    hipMemsetAsync(bcur, 0, NBUCK * sizeof(int), stream);
    k_encode  <<<782, 256, 0, stream>>>(x, W_enc, b_enc, W_gat, a_src, a_dst,
                                        hg, ssrc, sdst);
    if (a16)
        k_cvt <<<2048, 256, 0, stream>>>(attr, attr16);
    k_cscatter<<<NCHUNK, 1024, 0, stream>>>(srcp, dstp, bcur, ebuf);
    k_baggnode<<<NBUCK, 512, 0, stream>>>(ebuf, bcur, ssrc, sdst, hg,
                                          Wn1, bn1, Wn2, bn2, We1,
                                          p_src, p_dst, out);
    if (a16)
        k_edgehead<true><<<8192, 256, 0, stream>>>(srcp, dstp, attr, attr16,
                                                   p_src, p_dst, We1, be1, We2, be2,
                                                   out + (size_t)NN * NCLS);
    else
        k_edgehead<false><<<8192, 256, 0, stream>>>(srcp, dstp, attr, nullptr,
                                                    p_src, p_dst, We1, be1, We2, be2,
                                                    out + (size_t)NN * NCLS);
}

// Round 15
// 211.251 us; speedup vs baseline: 1.0330x; 1.0330x over previous
//
#include <hip/hip_runtime.h>
#include <hip/hip_bf16.h>

#define NN   100000
#define EE   1600000
#define DIN  128
#define HH   64
#define DEA  8
#define NCLS 2
#define BSZ  128                  // dst nodes per bucket
#define NBUCK ((NN + BSZ - 1) / BSZ)   // 782
#define CAPG 2368                 // per-bucket window capacity (mean 2046, sd ~45, +7 sigma)
#define CAP  4096                 // per-bucket LDS edge capacity in k_bagg2
#define NCHUNK 100                // scatter blocks; EE/NCHUNK = 16000 edges each, exact
#define CHUNK (EE / NCHUNK)

typedef __hip_bfloat16 bf16;
typedef short  short8 __attribute__((ext_vector_type(8)));
typedef float  f32x4  __attribute__((ext_vector_type(4)));

__device__ __forceinline__ void bf2x(unsigned u, float& lo, float& hi) {
    union { unsigned i; float f; } a, b;
    a.i = u << 16; b.i = u & 0xffff0000u;
    lo = a.f; hi = b.f;
}
__device__ __forceinline__ short f2bs(float f) {
    unsigned u = __float_as_uint(f);
    return (short)((u + 0x7fffu + ((u >> 16) & 1u)) >> 16);
}
__device__ __forceinline__ short8 cvt8(float4 a, float4 b) {
    short8 r;
    r[0] = f2bs(a.x); r[1] = f2bs(a.y); r[2] = f2bs(a.z); r[3] = f2bs(a.w);
    r[4] = f2bs(b.x); r[5] = f2bs(b.y); r[6] = f2bs(b.z); r[7] = f2bs(b.w);
    return r;
}
__device__ __forceinline__ f32x4 z4() {
    f32x4 z; z[0] = 0.f; z[1] = 0.f; z[2] = 0.f; z[3] = 0.f; return z;
}

// ---------- K2 (MFMA): h = relu(x@W_enc+b); hg = h@W_gat; s_src/s_dst = hg . a ----------
#define WE_STRIDE 136
#define WG_STRIDE 72
#define TB_STRIDE 68
__global__ __launch_bounds__(256) void k_encode(
        const float* __restrict__ x,
        const float* __restrict__ W_enc, const float* __restrict__ b_enc,
        const float* __restrict__ W_gat,
        const float* __restrict__ a_src, const float* __restrict__ a_dst,
        bf16* __restrict__ hg_, float* __restrict__ s_src, float* __restrict__ s_dst) {
    __shared__ short wencT[64 * WE_STRIDE];
    __shared__ short wgatT[64 * WG_STRIDE];
    __shared__ float tb[4][16 * TB_STRIDE];
    short* hg = (short*)hg_;
    int tid = threadIdx.x;
    for (int i = tid; i < DIN * HH; i += 256) {
        int k = i >> 6, n = i & 63;
        wencT[n * WE_STRIDE + k] = f2bs(W_enc[i]);
    }
    for (int i = tid; i < HH * HH; i += 256) {
        int k = i >> 6, n = i & 63;
        wgatT[n * WG_STRIDE + k] = f2bs(W_gat[i]);
    }
    __syncthreads();
    int w = tid >> 6, l = tid & 63, m = l & 15, h = l >> 4;
    short8 wg[2][4];
    #pragma unroll
    for (int kt = 0; kt < 2; kt++)
        #pragma unroll
        for (int nt = 0; nt < 4; nt++)
            wg[kt][nt] = *(short8*)&wgatT[(nt * 16 + m) * WG_STRIDE + kt * 32 + h * 8];
    float avs[4], avd[4], ben[4];
    #pragma unroll
    for (int nt = 0; nt < 4; nt++) {
        avs[nt] = a_src[nt * 16 + m];
        avd[nt] = a_dst[nt * 16 + m];
        ben[nt] = b_enc[nt * 16 + m];
    }
    int tp = blockIdx.x * 4 + w;
    if (tp >= NN / 32) return;
    int n0 = tp * 32;
    float* tbw = tb[w];

    f32x4 acc1[2][4];
    #pragma unroll
    for (int rt = 0; rt < 2; rt++)
        #pragma unroll
        for (int nt = 0; nt < 4; nt++) acc1[rt][nt] = z4();
    #pragma unroll
    for (int kt = 0; kt < 4; kt++) {
        short8 af[2];
        #pragma unroll
        for (int rt = 0; rt < 2; rt++) {
            const float* xp = &x[(size_t)(n0 + rt * 16 + m) * DIN + kt * 32 + h * 8];
            af[rt] = cvt8(*(const float4*)xp, *(const float4*)(xp + 4));
        }
        #pragma unroll
        for (int nt = 0; nt < 4; nt++) {
            short8 bf = *(short8*)&wencT[(nt * 16 + m) * WE_STRIDE + kt * 32 + h * 8];
            acc1[0][nt] = __builtin_amdgcn_mfma_f32_16x16x32_bf16(af[0], bf, acc1[0][nt], 0, 0, 0);
            acc1[1][nt] = __builtin_amdgcn_mfma_f32_16x16x32_bf16(af[1], bf, acc1[1][nt], 0, 0, 0);
        }
    }
    #pragma unroll
    for (int rt = 0; rt < 2; rt++) {
        #pragma unroll
        for (int nt = 0; nt < 4; nt++)
            #pragma unroll
            for (int r = 0; r < 4; r++) {
                float hv = fmaxf(acc1[rt][nt][r] + ben[nt], 0.f);
                tbw[(h * 4 + r) * TB_STRIDE + nt * 16 + m] = hv;
            }
        f32x4 acc2[4];
        #pragma unroll
        for (int nt = 0; nt < 4; nt++) acc2[nt] = z4();
        #pragma unroll
        for (int kt = 0; kt < 2; kt++) {
            const float* tp_ = &tbw[m * TB_STRIDE + kt * 32 + h * 8];
            short8 af2 = cvt8(*(const float4*)tp_, *(const float4*)(tp_ + 4));
            #pragma unroll
            for (int nt = 0; nt < 4; nt++)
                acc2[nt] = __builtin_amdgcn_mfma_f32_16x16x32_bf16(af2, wg[kt][nt], acc2[nt], 0, 0, 0);
        }
        float ps[4] = {0.f, 0.f, 0.f, 0.f}, pd[4] = {0.f, 0.f, 0.f, 0.f};
        #pragma unroll
        for (int nt = 0; nt < 4; nt++)
            #pragma unroll
            for (int r = 0; r < 4; r++) {
                float v = acc2[nt][r];
                ps[r] = fmaf(v, avs[nt], ps[r]);
                pd[r] = fmaf(v, avd[nt], pd[r]);
                hg[(size_t)(n0 + rt * 16 + h * 4 + r) * HH + nt * 16 + m] = f2bs(v);
            }
        #pragma unroll
        for (int off = 1; off < 16; off <<= 1)
            #pragma unroll
            for (int r = 0; r < 4; r++) {
                ps[r] += __shfl_xor(ps[r], off);
                pd[r] += __shfl_xor(pd[r], off);
            }
        if (m == 0) {
            *(float4*)&s_src[n0 + rt * 16 + h * 4] = make_float4(ps[0], ps[1], ps[2], ps[3]);
            *(float4*)&s_dst[n0 + rt * 16 + h * 4] = make_float4(pd[0], pd[1], pd[2], pd[3]);
        }
    }
}

// ---------- K-cvt: attr f32 -> bf16, full-GPU streaming ----------
__global__ __launch_bounds__(256) void k_cvt(const float* __restrict__ attr,
                                             short* __restrict__ attr16) {
    int i = blockIdx.x * blockDim.x + threadIdx.x;
    int stride = gridDim.x * blockDim.x;
    for (int j = i; j < EE * DEA / 8; j += stride) {
        const float4* p = (const float4*)(attr + (size_t)j * 8);
        *(short8*)(attr16 + (size_t)j * 8) = cvt8(p[0], p[1]);
    }
}

// ---------- B3': two-level scatter (pure), 1024 thr/block, 100 blocks ----------
__global__ __launch_bounds__(1024) void k_cscatter(
        const int* __restrict__ src, const int* __restrict__ dst,
        int* bcur, unsigned* __restrict__ ebuf) {
    __shared__ int cnt[NBUCK];
    __shared__ int cur[NBUCK];
    int tid = threadIdx.x;
    int e0 = blockIdx.x * CHUNK;
    for (int i = tid; i < NBUCK; i += 1024) cnt[i] = 0;
    __syncthreads();
    for (int i = tid; i < CHUNK; i += 1024)
        atomicAdd(&cnt[dst[e0 + i] >> 7], 1);          // BSZ = 128
    __syncthreads();
    for (int i = tid; i < NBUCK; i += 1024) {
        int c = cnt[i];
        int base = c ? atomicAdd(&bcur[i], c) : 0;     // reserve range in bucket window
        cur[i] = i * CAPG + base;
    }
    __syncthreads();
    for (int i = tid; i < CHUNK; i += 1024) {
        int dv = dst[e0 + i], sv = src[e0 + i];
        int b  = dv >> 7;
        int dl = dv & (BSZ - 1);
        int pos = atomicAdd(&cur[b], 1);
        ebuf[pos] = ((unsigned)dl << 24) | (unsigned)sv;
    }
}

// ---------- B4: per-bucket counting sort in LDS, then wave-per-node register agg ----------
// Writes agg as bf16 (halves the bagg2->nodehead traffic). 35 KB LDS -> 4 blocks/CU.
__global__ __launch_bounds__(512) void k_bagg2(
        const unsigned* __restrict__ ebuf, const int* __restrict__ bcur,
        const float* __restrict__ s_src, const float* __restrict__ s_dst,
        const bf16* __restrict__ hg, bf16* __restrict__ agg_) {
    __shared__ unsigned sl[CAP];
    __shared__ int cnt[BSZ];
    __shared__ int sstart[BSZ];
    __shared__ int spos[BSZ];
    __shared__ int sscan[BSZ];
    short* agg = (short*)agg_;
    int tid = threadIdx.x;
    int b = blockIdx.x;
    int rs = b * CAPG;
    int ne = min(bcur[b], CAP);
    for (int i = tid; i < BSZ; i += 512) cnt[i] = 0;
    __syncthreads();
    for (int i = tid; i < ne; i += 512)
        atomicAdd(&cnt[ebuf[rs + i] >> 24], 1);
    __syncthreads();
    int v = (tid < BSZ) ? cnt[tid] : 0;
    if (tid < BSZ) sscan[tid] = v;
    __syncthreads();
    for (int s = 1; s < BSZ; s <<= 1) {
        int add = (tid < BSZ && tid >= s) ? sscan[tid - s] : 0;
        __syncthreads();
        if (tid < BSZ) sscan[tid] += add;
        __syncthreads();
    }
    if (tid < BSZ) { sstart[tid] = sscan[tid] - v; spos[tid] = sscan[tid] - v; }
    __syncthreads();
    for (int i = tid; i < ne; i += 512) {
        unsigned p = ebuf[rs + i];
        int dl = p >> 24;
        int q = atomicAdd(&spos[dl], 1);
        sl[q] = p & 0xFFFFFFu;
    }
    __syncthreads();
    int lane = tid & 63, wv = tid >> 6;
    int lane8 = lane & 7, grp = lane >> 3;
    for (int dl = wv; dl < BSZ; dl += 8) {
        int node = b * BSZ + dl;
        if (node >= NN) break;
        int st = sstart[dl], deg = cnt[dl];
        float sd = s_dst[node];
        float a[8] = {0.f}, denom = 0.f;
        for (int i = grp; i < deg; i += 8) {
            int sv = sl[st + i];
            float s = s_src[sv] + sd;
            s = (s >= 0.f) ? s : 0.2f * s;    // leaky_relu 0.2
            float ex = __expf(s);
            denom += ex;
            uint4 u = *(const uint4*)&hg[(size_t)sv * HH + lane8 * 8];
            float f0, f1, f2, f3, f4, f5, f6, f7;
            bf2x(u.x, f0, f1); bf2x(u.y, f2, f3);
            bf2x(u.z, f4, f5); bf2x(u.w, f6, f7);
            a[0] = fmaf(ex, f0, a[0]); a[1] = fmaf(ex, f1, a[1]);
            a[2] = fmaf(ex, f2, a[2]); a[3] = fmaf(ex, f3, a[3]);
            a[4] = fmaf(ex, f4, a[4]); a[5] = fmaf(ex, f5, a[5]);
            a[6] = fmaf(ex, f6, a[6]); a[7] = fmaf(ex, f7, a[7]);
        }
        #pragma unroll
        for (int off = 8; off < 64; off <<= 1) {
            #pragma unroll
            for (int j = 0; j < 8; j++) a[j] += __shfl_xor(a[j], off);
            denom += __shfl_xor(denom, off);
        }
        if (lane < 8) {
            float inv = 1.f / (denom + 1e-9f);
            short8 r;
            #pragma unroll
            for (int j = 0; j < 8; j++) r[j] = f2bs(a[j] * inv);
            *(short8*)&agg[(size_t)node * HH + lane8 * 8] = r;
        }
    }
}

// ---------- K7 (MFMA): xc=relu(agg bf16); [xc]@[Wn1|We1s|We1d]; logits + bf16 partials ----
#define WC_STRIDE 72
__global__ __launch_bounds__(256) void k_nodehead(
        const bf16* __restrict__ agg_,
        const float* __restrict__ Wn1, const float* __restrict__ bn1,
        const float* __restrict__ Wn2, const float* __restrict__ bn2,
        const float* __restrict__ We1,
        bf16* __restrict__ p_src_, bf16* __restrict__ p_dst_, float* __restrict__ out_node) {
    __shared__ short wcatT[192 * WC_STRIDE];   // 27648 B
    const short* agg = (const short*)agg_;
    short* p_src = (short*)p_src_;
    short* p_dst = (short*)p_dst_;
    int tid = threadIdx.x;
    for (int i = tid; i < 3 * HH * HH; i += 256) {
        int mat = i >> 12, j = i & 4095;
        int k = j >> 6, l2 = j & 63;
        float v = (mat == 0) ? Wn1[j] : (mat == 1 ? We1[j] : We1[HH * HH + j]);
        wcatT[(mat * 64 + l2) * WC_STRIDE + k] = f2bs(v);
    }
    __syncthreads();
    int w = tid >> 6, l = tid & 63, m = l & 15, h = l >> 4;
    int tp = blockIdx.x * 4 + w;
    if (tp >= NN / 32) return;
    int n0 = tp * 32;
    float ben[4], wn2a[4], wn2b[4];
    #pragma unroll
    for (int nt = 0; nt < 4; nt++) {
        ben[nt]  = bn1[nt * 16 + m];
        wn2a[nt] = Wn2[(nt * 16 + m) * NCLS + 0];
        wn2b[nt] = Wn2[(nt * 16 + m) * NCLS + 1];
    }
    float bn20 = bn2[0], bn21 = bn2[1];
    #pragma unroll
    for (int rt = 0; rt < 2; rt++) {
        f32x4 acc[12];
        #pragma unroll
        for (int nt = 0; nt < 12; nt++) acc[nt] = z4();
        #pragma unroll
        for (int kt = 0; kt < 2; kt++) {
            short8 v = *(const short8*)&agg[(size_t)(n0 + rt * 16 + m) * HH + kt * 32 + h * 8];
            short8 af;
            #pragma unroll
            for (int j = 0; j < 8; j++) af[j] = (v[j] < 0) ? (short)0 : v[j];  // exact relu
            #pragma unroll
            for (int nt = 0; nt < 12; nt++) {
                short8 bf = *(short8*)&wcatT[(nt * 16 + m) * WC_STRIDE + kt * 32 + h * 8];
                acc[nt] = __builtin_amdgcn_mfma_f32_16x16x32_bf16(af, bf, acc[nt], 0, 0, 0);
            }
        }
        float l0[4] = {0.f, 0.f, 0.f, 0.f}, l1[4] = {0.f, 0.f, 0.f, 0.f};
        #pragma unroll
        for (int nt = 0; nt < 4; nt++)
            #pragma unroll
            for (int r = 0; r < 4; r++) {
                float t = fmaxf(acc[nt][r] + ben[nt], 0.f);
                l0[r] = fmaf(t, wn2a[nt], l0[r]);
                l1[r] = fmaf(t, wn2b[nt], l1[r]);
            }
        #pragma unroll
        for (int nt = 0; nt < 4; nt++)
            #pragma unroll
            for (int r = 0; r < 4; r++) {
                size_t row = (size_t)(n0 + rt * 16 + h * 4 + r) * HH + nt * 16 + m;
                p_src[row] = f2bs(acc[nt + 4][r]);
                p_dst[row] = f2bs(acc[nt + 8][r]);
            }
        #pragma unroll
        for (int off = 1; off < 16; off <<= 1)
            #pragma unroll
            for (int r = 0; r < 4; r++) {
                l0[r] += __shfl_xor(l0[r], off);
                l1[r] += __shfl_xor(l1[r], off);
            }
        if (m == 0) {
            #pragma unroll
            for (int r = 0; r < 4; r++)
                *(float2*)&out_node[(size_t)(n0 + rt * 16 + h * 4 + r) * NCLS] =
                    make_float2(l0[r] + bn20, l1[r] + bn21);
        }
    }
}

// ---------- K8: edge head. 16 lanes per 4-edge group; A16 selects bf16 attr stream. ----
template<bool A16>
__global__ __launch_bounds__(256) void k_edgehead(
        const int* __restrict__ src, const int* __restrict__ dst,
        const float* __restrict__ edge_attr, const short* __restrict__ attr16,
        const bf16* __restrict__ p_src, const bf16* __restrict__ p_dst,
        const float* __restrict__ We1, const float* __restrict__ be1,
        const float* __restrict__ We2, const float* __restrict__ be2,
        float* __restrict__ out_edge) {
    int tid = threadIdx.x;
    int lane16 = tid & 15;
    int grp    = (tid & 63) >> 4;
    int wave   = tid >> 6;
    float w1a[DEA][4], w2c0[4], w2c1[4], b1v[4];
    #pragma unroll
    for (int d = 0; d < DEA; d++) {
        float4 v = *(const float4*)&We1[(2 * HH + d) * HH + lane16 * 4];
        w1a[d][0] = v.x; w1a[d][1] = v.y; w1a[d][2] = v.z; w1a[d][3] = v.w;
    }
    float4 bv = *(const float4*)&be1[lane16 * 4];
    b1v[0] = bv.x; b1v[1] = bv.y; b1v[2] = bv.z; b1v[3] = bv.w;
    #pragma unroll
    for (int j = 0; j < 4; j++) {
        w2c0[j] = We2[(lane16 * 4 + j) * NCLS + 0];
        w2c1[j] = We2[(lane16 * 4 + j) * NCLS + 1];
    }
    float be20 = be2[0], be21 = be2[1];

    int stride = gridDim.x * 64;   // 64 edges per block-iteration; EE%64==0
    for (int e = blockIdx.x * 64 + wave * 16 + grp * 4; e < EE; e += stride) {
        int sv[4], dv[4];
        #pragma unroll
        for (int q = 0; q < 4; q++) { sv[q] = src[e + q]; dv[q] = dst[e + q]; }
        uint2 us[4], ud[4];
        uint4 ua[4];
        float4 at0[4], at1[4];
        #pragma unroll
        for (int q = 0; q < 4; q++) {
            us[q] = *(const uint2*)&p_src[(size_t)sv[q] * HH + lane16 * 4];
            ud[q] = *(const uint2*)&p_dst[(size_t)dv[q] * HH + lane16 * 4];
            if constexpr (A16) {
                ua[q] = *(const uint4*)&attr16[(size_t)(e + q) * DEA];
            } else {
                at0[q] = *(const float4*)&edge_attr[(size_t)(e + q) * DEA];
                at1[q] = *(const float4*)&edge_attr[(size_t)(e + q) * DEA + 4];
            }
        }
        float l0[4], l1[4];
        #pragma unroll
        for (int q = 0; q < 4; q++) {
            float s0, s1, s2, s3, d0, d1, d2, d3;
            bf2x(us[q].x, s0, s1); bf2x(us[q].y, s2, s3);
            bf2x(ud[q].x, d0, d1); bf2x(ud[q].y, d2, d3);
            float t[4] = {s0 + d0 + b1v[0], s1 + d1 + b1v[1],
                          s2 + d2 + b1v[2], s3 + d3 + b1v[3]};
            float av[DEA];
            if constexpr (A16) {
                bf2x(ua[q].x, av[0], av[1]); bf2x(ua[q].y, av[2], av[3]);
                bf2x(ua[q].z, av[4], av[5]); bf2x(ua[q].w, av[6], av[7]);
            } else {
                av[0] = at0[q].x; av[1] = at0[q].y; av[2] = at0[q].z; av[3] = at0[q].w;
                av[4] = at1[q].x; av[5] = at1[q].y; av[6] = at1[q].z; av[7] = at1[q].w;
            }
            l0[q] = 0.f; l1[q] = 0.f;
            #pragma unroll
            for (int j = 0; j < 4; j++) {
                #pragma unroll
                for (int d = 0; d < DEA; d++) t[j] = fmaf(av[d], w1a[d][j], t[j]);
                float r = fmaxf(t[j], 0.f);
                l0[q] = fmaf(r, w2c0[j], l0[q]);
                l1[q] = fmaf(r, w2c1[j], l1[q]);
            }
        }
        #pragma unroll
        for (int off = 8; off; off >>= 1)
            #pragma unroll
            for (int q = 0; q < 4; q++) {
                l0[q] += __shfl_xor(l0[q], off);
                l1[q] += __shfl_xor(l1[q], off);
            }
        if (lane16 == 0) {
            #pragma unroll
            for (int q = 0; q < 4; q++)
                *(float2*)&out_edge[(size_t)(e + q) * NCLS] =
                    make_float2(l0[q] + be20, l1[q] + be21);
        }
    }
}

extern "C" void kernel_launch(void* const* d_in, const int* in_sizes, int n_in,
                              void* d_out, int out_size, void* d_ws, size_t ws_size,
                              hipStream_t stream) {
    const float* x      = (const float*)d_in[0];
    const int*   ei     = (const int*)  d_in[1];
    const float* attr   = (const float*)d_in[2];
    const float* W_enc  = (const float*)d_in[3];
    const float* b_enc  = (const float*)d_in[4];
    const float* W_gat  = (const float*)d_in[5];
    const float* a_src  = (const float*)d_in[6];
    const float* a_dst  = (const float*)d_in[7];
    const float* Wn1    = (const float*)d_in[8];
    const float* bn1    = (const float*)d_in[9];
    const float* Wn2    = (const float*)d_in[10];
    const float* bn2    = (const float*)d_in[11];
    const float* We1    = (const float*)d_in[12];
    const float* be1    = (const float*)d_in[13];
    const float* We2    = (const float*)d_in[14];
    const float* be2    = (const float*)d_in[15];
    float* out = (float*)d_out;
    float* ws  = (float*)d_ws;

    // workspace layout (float units), ~72.2 MB (fit in R13/R14):
    bf16*     hg_psrc = (bf16*)ws;                        // [N*H] bf16: hg, later p_src
    bf16*     agg     = (bf16*)(ws + (size_t)NN * 32);    // [N*H] bf16
    bf16*     p_dst   = (bf16*)(ws + (size_t)NN * 64);    // [N*H] bf16
    float*    ssrc    = ws + (size_t)NN * 96;             // [N]
    float*    sdst    = ssrc + NN;                        // [N]
    int*      bcur    = (int*)(sdst + NN);                // [NBUCK] count cursors
    unsigned* ebuf    = (unsigned*)(bcur + 1024);         // [NBUCK*CAPG] bucket windows
    short*    attr16  = (short*)(ebuf + (size_t)NBUCK * CAPG);  // [E*DEA] bf16 (optional)
    size_t    need    = (size_t)((char*)(attr16 + (size_t)EE * DEA) - (char*)ws);
    bool      a16     = ws_size >= need;                  // deterministic per-session

    const int* srcp = ei;
    const int* dstp = ei + EE;

    hipMemsetAsync(bcur, 0, NBUCK * sizeof(int), stream);
    k_encode  <<<782, 256, 0, stream>>>(x, W_enc, b_enc, W_gat, a_src, a_dst,
                                        hg_psrc, ssrc, sdst);
    if (a16)
        k_cvt <<<2048, 256, 0, stream>>>(attr, attr16);
    k_cscatter<<<NCHUNK, 1024, 0, stream>>>(srcp, dstp, bcur, ebuf);
    k_bagg2   <<<NBUCK, 512, 0, stream>>>(ebuf, bcur, ssrc, sdst, hg_psrc, agg);
    k_nodehead<<<782, 256, 0, stream>>>(agg, Wn1, bn1, Wn2, bn2, We1,
                                        hg_psrc /*p_src*/, p_dst, out);
    if (a16)
        k_edgehead<true><<<8192, 256, 0, stream>>>(srcp, dstp, attr, attr16,
                                                   hg_psrc, p_dst, We1, be1, We2, be2,
                                                   out + (size_t)NN * NCLS);
    else
        k_edgehead<false><<<8192, 256, 0, stream>>>(srcp, dstp, attr, nullptr,
                                                    hg_psrc, p_dst, We1, be1, We2, be2,
                                                    out + (size_t)NN * NCLS);
}

// Round 16
// 193.783 us; speedup vs baseline: 1.1261x; 1.0901x over previous
//
#include <hip/hip_runtime.h>
#include <hip/hip_bf16.h>

#define NN   100000
#define EE   1600000
#define DIN  128
#define HH   64
#define DEA  8
#define NCLS 2
#define BSZ  128                  // dst nodes per bucket
#define NBUCK ((NN + BSZ - 1) / BSZ)   // 782
#define CAPG 2368                 // per-bucket window capacity (mean 2046, sd ~45, +7 sigma)
#define NCHUNK 100                // scatter blocks; EE/NCHUNK = 16000 edges each, exact
#define CHUNK (EE / NCHUNK)
#define NENC 391                  // encode blocks: 391*8 = 3128 tile-pairs >= 3125
#define NCVT 160                  // cvt blocks

typedef __hip_bfloat16 bf16;
typedef short  short8 __attribute__((ext_vector_type(8)));
typedef float  f32x4  __attribute__((ext_vector_type(4)));

__device__ __forceinline__ void bf2x(unsigned u, float& lo, float& hi) {
    union { unsigned i; float f; } a, b;
    a.i = u << 16; b.i = u & 0xffff0000u;
    lo = a.f; hi = b.f;
}
__device__ __forceinline__ short f2bs(float f) {
    unsigned u = __float_as_uint(f);
    return (short)((u + 0x7fffu + ((u >> 16) & 1u)) >> 16);
}
__device__ __forceinline__ short8 cvt8(float4 a, float4 b) {
    short8 r;
    r[0] = f2bs(a.x); r[1] = f2bs(a.y); r[2] = f2bs(a.z); r[3] = f2bs(a.w);
    r[4] = f2bs(b.x); r[5] = f2bs(b.y); r[6] = f2bs(b.z); r[7] = f2bs(b.w);
    return r;
}
__device__ __forceinline__ f32x4 z4() {
    f32x4 z; z[0] = 0.f; z[1] = 0.f; z[2] = 0.f; z[3] = 0.f; return z;
}

// ---------- K-front: heterogeneous block roles — encode | cscatter | cvt (independent) ----
#define WE_STRIDE 136
#define WG_STRIDE 72
#define TB_STRIDE 68
union FrontLDS {
    struct {
        short wencT[64 * WE_STRIDE];      // 17408 B
        short wgatT[64 * WG_STRIDE];      //  9216 B
        float tb[8][16 * TB_STRIDE];      // 34816 B  -> 61440 B total
    } e;
    struct {
        int cnt[NBUCK];
        int cur[NBUCK];                   // 6256 B
    } s;
};

__global__ __launch_bounds__(512) void k_front(
        const float* __restrict__ x,
        const float* __restrict__ W_enc, const float* __restrict__ b_enc,
        const float* __restrict__ W_gat,
        const float* __restrict__ a_src, const float* __restrict__ a_dst,
        bf16* __restrict__ hg_, float* __restrict__ s_src, float* __restrict__ s_dst,
        const int* __restrict__ src, const int* __restrict__ dst,
        int* bcur, unsigned* __restrict__ ebuf,
        const float* __restrict__ attr, short* __restrict__ attr16) {
    __shared__ FrontLDS u;
    int bid = blockIdx.x;
    int tid = threadIdx.x;

    if (bid < NENC) {
        // ---- encode role: h = relu(x@W_enc+b); hg = h@W_gat; s_src/s_dst = hg . a ----
        short* hg = (short*)hg_;
        for (int i = tid; i < DIN * HH; i += 512) {
            int k = i >> 6, n = i & 63;
            u.e.wencT[n * WE_STRIDE + k] = f2bs(W_enc[i]);
        }
        for (int i = tid; i < HH * HH; i += 512) {
            int k = i >> 6, n = i & 63;
            u.e.wgatT[n * WG_STRIDE + k] = f2bs(W_gat[i]);
        }
        __syncthreads();
        int w = tid >> 6, l = tid & 63, m = l & 15, h = l >> 4;
        short8 wg[2][4];
        #pragma unroll
        for (int kt = 0; kt < 2; kt++)
            #pragma unroll
            for (int nt = 0; nt < 4; nt++)
                wg[kt][nt] = *(short8*)&u.e.wgatT[(nt * 16 + m) * WG_STRIDE + kt * 32 + h * 8];
        float avs[4], avd[4], ben[4];
        #pragma unroll
        for (int nt = 0; nt < 4; nt++) {
            avs[nt] = a_src[nt * 16 + m];
            avd[nt] = a_dst[nt * 16 + m];
            ben[nt] = b_enc[nt * 16 + m];
        }
        int tp = bid * 8 + w;                    // 8 tile-pairs per block
        if (tp >= NN / 32) return;               // per-wave guard; tb is wave-local
        int n0 = tp * 32;
        float* tbw = u.e.tb[w];

        f32x4 acc1[2][4];
        #pragma unroll
        for (int rt = 0; rt < 2; rt++)
            #pragma unroll
            for (int nt = 0; nt < 4; nt++) acc1[rt][nt] = z4();
        #pragma unroll
        for (int kt = 0; kt < 4; kt++) {
            short8 af[2];
            #pragma unroll
            for (int rt = 0; rt < 2; rt++) {
                const float* xp = &x[(size_t)(n0 + rt * 16 + m) * DIN + kt * 32 + h * 8];
                af[rt] = cvt8(*(const float4*)xp, *(const float4*)(xp + 4));
            }
            #pragma unroll
            for (int nt = 0; nt < 4; nt++) {
                short8 bf = *(short8*)&u.e.wencT[(nt * 16 + m) * WE_STRIDE + kt * 32 + h * 8];
                acc1[0][nt] = __builtin_amdgcn_mfma_f32_16x16x32_bf16(af[0], bf, acc1[0][nt], 0, 0, 0);
                acc1[1][nt] = __builtin_amdgcn_mfma_f32_16x16x32_bf16(af[1], bf, acc1[1][nt], 0, 0, 0);
            }
        }
        #pragma unroll
        for (int rt = 0; rt < 2; rt++) {
            #pragma unroll
            for (int nt = 0; nt < 4; nt++)
                #pragma unroll
                for (int r = 0; r < 4; r++) {
                    float hv = fmaxf(acc1[rt][nt][r] + ben[nt], 0.f);
                    tbw[(h * 4 + r) * TB_STRIDE + nt * 16 + m] = hv;
                }
            f32x4 acc2[4];
            #pragma unroll
            for (int nt = 0; nt < 4; nt++) acc2[nt] = z4();
            #pragma unroll
            for (int kt = 0; kt < 2; kt++) {
                const float* pptr = &tbw[m * TB_STRIDE + kt * 32 + h * 8];
                short8 af2 = cvt8(*(const float4*)pptr, *(const float4*)(pptr + 4));
                #pragma unroll
                for (int nt = 0; nt < 4; nt++)
                    acc2[nt] = __builtin_amdgcn_mfma_f32_16x16x32_bf16(af2, wg[kt][nt], acc2[nt], 0, 0, 0);
            }
            float ps[4] = {0.f, 0.f, 0.f, 0.f}, pd[4] = {0.f, 0.f, 0.f, 0.f};
            #pragma unroll
            for (int nt = 0; nt < 4; nt++)
                #pragma unroll
                for (int r = 0; r < 4; r++) {
                    float v = acc2[nt][r];
                    ps[r] = fmaf(v, avs[nt], ps[r]);
                    pd[r] = fmaf(v, avd[nt], pd[r]);
                    hg[(size_t)(n0 + rt * 16 + h * 4 + r) * HH + nt * 16 + m] = f2bs(v);
                }
            #pragma unroll
            for (int off = 1; off < 16; off <<= 1)
                #pragma unroll
                for (int r = 0; r < 4; r++) {
                    ps[r] += __shfl_xor(ps[r], off);
                    pd[r] += __shfl_xor(pd[r], off);
                }
            if (m == 0) {
                *(float4*)&s_src[n0 + rt * 16 + h * 4] = make_float4(ps[0], ps[1], ps[2], ps[3]);
                *(float4*)&s_dst[n0 + rt * 16 + h * 4] = make_float4(pd[0], pd[1], pd[2], pd[3]);
            }
        }
    } else if (bid < NENC + NCHUNK) {
        // ---- cscatter role: two-level scatter; reservation depth stays NCHUNK=100 ----
        int cb = bid - NENC;
        int e0 = cb * CHUNK;
        for (int i = tid; i < NBUCK; i += 512) u.s.cnt[i] = 0;
        __syncthreads();
        for (int i = tid; i < CHUNK; i += 512)
            atomicAdd(&u.s.cnt[dst[e0 + i] >> 7], 1);          // BSZ = 128
        __syncthreads();
        for (int i = tid; i < NBUCK; i += 512) {
            int c = u.s.cnt[i];
            int base = c ? atomicAdd(&bcur[i], c) : 0;         // reserve range in window
            u.s.cur[i] = i * CAPG + base;
        }
        __syncthreads();
        for (int i = tid; i < CHUNK; i += 512) {
            int dv = dst[e0 + i], sv = src[e0 + i];
            int b  = dv >> 7;
            int dl = dv & (BSZ - 1);
            int pos = atomicAdd(&u.s.cur[b], 1);
            ebuf[pos] = ((unsigned)dl << 24) | (unsigned)sv;
        }
    } else {
        // ---- cvt role: attr f32 -> bf16 streaming ----
        if (!attr16) return;
        int cvb = bid - NENC - NCHUNK;
        int stride = NCVT * 512;
        for (int j = cvb * 512 + tid; j < EE * DEA / 8; j += stride) {
            const float4* p = (const float4*)(attr + (size_t)j * 8);
            *(short8*)(attr16 + (size_t)j * 8) = cvt8(p[0], p[1]);
        }
    }
}

// ---------- B4: per-bucket counting sort in LDS, then wave-per-node register agg ----------
// sl trimmed to CAPG (window capacity) -> 28.4 KB LDS -> 5 blocks/CU.
__global__ __launch_bounds__(512) void k_bagg2(
        const unsigned* __restrict__ ebuf, const int* __restrict__ bcur,
        const float* __restrict__ s_src, const float* __restrict__ s_dst,
        const bf16* __restrict__ hg, bf16* __restrict__ agg_) {
    __shared__ unsigned sl[CAPG];
    __shared__ int cnt[BSZ];
    __shared__ int sstart[BSZ];
    __shared__ int spos[BSZ];
    __shared__ int sscan[BSZ];
    short* agg = (short*)agg_;
    int tid = threadIdx.x;
    int b = blockIdx.x;
    int rs = b * CAPG;
    int ne = min(bcur[b], CAPG);
    for (int i = tid; i < BSZ; i += 512) cnt[i] = 0;
    __syncthreads();
    for (int i = tid; i < ne; i += 512)
        atomicAdd(&cnt[ebuf[rs + i] >> 24], 1);
    __syncthreads();
    int v = (tid < BSZ) ? cnt[tid] : 0;
    if (tid < BSZ) sscan[tid] = v;
    __syncthreads();
    for (int s = 1; s < BSZ; s <<= 1) {
        int add = (tid < BSZ && tid >= s) ? sscan[tid - s] : 0;
        __syncthreads();
        if (tid < BSZ) sscan[tid] += add;
        __syncthreads();
    }
    if (tid < BSZ) { sstart[tid] = sscan[tid] - v; spos[tid] = sscan[tid] - v; }
    __syncthreads();
    for (int i = tid; i < ne; i += 512) {
        unsigned p = ebuf[rs + i];
        int dl = p >> 24;
        int q = atomicAdd(&spos[dl], 1);
        sl[q] = p & 0xFFFFFFu;
    }
    __syncthreads();
    int lane = tid & 63, wv = tid >> 6;
    int lane8 = lane & 7, grp = lane >> 3;
    for (int dl = wv; dl < BSZ; dl += 8) {
        int node = b * BSZ + dl;
        if (node >= NN) break;
        int st = sstart[dl], deg = cnt[dl];
        float sd = s_dst[node];
        float a[8] = {0.f}, denom = 0.f;
        for (int i = grp; i < deg; i += 8) {
            int sv = sl[st + i];
            float s = s_src[sv] + sd;
            s = (s >= 0.f) ? s : 0.2f * s;    // leaky_relu 0.2
            float ex = __expf(s);
            denom += ex;
            uint4 uu = *(const uint4*)&hg[(size_t)sv * HH + lane8 * 8];
            float f0, f1, f2, f3, f4, f5, f6, f7;
            bf2x(uu.x, f0, f1); bf2x(uu.y, f2, f3);
            bf2x(uu.z, f4, f5); bf2x(uu.w, f6, f7);
            a[0] = fmaf(ex, f0, a[0]); a[1] = fmaf(ex, f1, a[1]);
            a[2] = fmaf(ex, f2, a[2]); a[3] = fmaf(ex, f3, a[3]);
            a[4] = fmaf(ex, f4, a[4]); a[5] = fmaf(ex, f5, a[5]);
            a[6] = fmaf(ex, f6, a[6]); a[7] = fmaf(ex, f7, a[7]);
        }
        #pragma unroll
        for (int off = 8; off < 64; off <<= 1) {
            #pragma unroll
            for (int j = 0; j < 8; j++) a[j] += __shfl_xor(a[j], off);
            denom += __shfl_xor(denom, off);
        }
        if (lane < 8) {
            float inv = 1.f / (denom + 1e-9f);
            short8 r;
            #pragma unroll
            for (int j = 0; j < 8; j++) r[j] = f2bs(a[j] * inv);
            *(short8*)&agg[(size_t)node * HH + lane8 * 8] = r;
        }
    }
}

// ---------- K7 (MFMA): xc=relu(agg bf16); [xc]@[Wn1|We1s|We1d]; logits + bf16 partials ----
#define WC_STRIDE 72
__global__ __launch_bounds__(256) void k_nodehead(
        const bf16* __restrict__ agg_,
        const float* __restrict__ Wn1, const float* __restrict__ bn1,
        const float* __restrict__ Wn2, const float* __restrict__ bn2,
        const float* __restrict__ We1,
        bf16* __restrict__ p_src_, bf16* __restrict__ p_dst_, float* __restrict__ out_node) {
    __shared__ short wcatT[192 * WC_STRIDE];   // 27648 B
    const short* agg = (const short*)agg_;
    short* p_src = (short*)p_src_;
    short* p_dst = (short*)p_dst_;
    int tid = threadIdx.x;
    for (int i = tid; i < 3 * HH * HH; i += 256) {
        int mat = i >> 12, j = i & 4095;
        int k = j >> 6, l2 = j & 63;
        float v = (mat == 0) ? Wn1[j] : (mat == 1 ? We1[j] : We1[HH * HH + j]);
        wcatT[(mat * 64 + l2) * WC_STRIDE + k] = f2bs(v);
    }
    __syncthreads();
    int w = tid >> 6, l = tid & 63, m = l & 15, h = l >> 4;
    int tp = blockIdx.x * 4 + w;
    if (tp >= NN / 32) return;
    int n0 = tp * 32;
    float ben[4], wn2a[4], wn2b[4];
    #pragma unroll
    for (int nt = 0; nt < 4; nt++) {
        ben[nt]  = bn1[nt * 16 + m];
        wn2a[nt] = Wn2[(nt * 16 + m) * NCLS + 0];
        wn2b[nt] = Wn2[(nt * 16 + m) * NCLS + 1];
    }
    float bn20 = bn2[0], bn21 = bn2[1];
    #pragma unroll
    for (int rt = 0; rt < 2; rt++) {
        f32x4 acc[12];
        #pragma unroll
        for (int nt = 0; nt < 12; nt++) acc[nt] = z4();
        #pragma unroll
        for (int kt = 0; kt < 2; kt++) {
            short8 v = *(const short8*)&agg[(size_t)(n0 + rt * 16 + m) * HH + kt * 32 + h * 8];
            short8 af;
            #pragma unroll
            for (int j = 0; j < 8; j++) af[j] = (v[j] < 0) ? (short)0 : v[j];  // exact relu
            #pragma unroll
            for (int nt = 0; nt < 12; nt++) {
                short8 bf = *(short8*)&wcatT[(nt * 16 + m) * WC_STRIDE + kt * 32 + h * 8];
                acc[nt] = __builtin_amdgcn_mfma_f32_16x16x32_bf16(af, bf, acc[nt], 0, 0, 0);
            }
        }
        float l0[4] = {0.f, 0.f, 0.f, 0.f}, l1[4] = {0.f, 0.f, 0.f, 0.f};
        #pragma unroll
        for (int nt = 0; nt < 4; nt++)
            #pragma unroll
            for (int r = 0; r < 4; r++) {
                float t = fmaxf(acc[nt][r] + ben[nt], 0.f);
                l0[r] = fmaf(t, wn2a[nt], l0[r]);
                l1[r] = fmaf(t, wn2b[nt], l1[r]);
            }
        #pragma unroll
        for (int nt = 0; nt < 4; nt++)
            #pragma unroll
            for (int r = 0; r < 4; r++) {
                size_t row = (size_t)(n0 + rt * 16 + h * 4 + r) * HH + nt * 16 + m;
                p_src[row] = f2bs(acc[nt + 4][r]);
                p_dst[row] = f2bs(acc[nt + 8][r]);
            }
        #pragma unroll
        for (int off = 1; off < 16; off <<= 1)
            #pragma unroll
            for (int r = 0; r < 4; r++) {
                l0[r] += __shfl_xor(l0[r], off);
                l1[r] += __shfl_xor(l1[r], off);
            }
        if (m == 0) {
            #pragma unroll
            for (int r = 0; r < 4; r++)
                *(float2*)&out_node[(size_t)(n0 + rt * 16 + h * 4 + r) * NCLS] =
                    make_float2(l0[r] + bn20, l1[r] + bn21);
        }
    }
}

// ---------- K8: edge head. 16 lanes per 4-edge group; A16 selects bf16 attr stream. ----
template<bool A16>
__global__ __launch_bounds__(256) void k_edgehead(
        const int* __restrict__ src, const int* __restrict__ dst,
        const float* __restrict__ edge_attr, const short* __restrict__ attr16,
        const bf16* __restrict__ p_src, const bf16* __restrict__ p_dst,
        const float* __restrict__ We1, const float* __restrict__ be1,
        const float* __restrict__ We2, const float* __restrict__ be2,
        float* __restrict__ out_edge) {
    int tid = threadIdx.x;
    int lane16 = tid & 15;
    int grp    = (tid & 63) >> 4;
    int wave   = tid >> 6;
    float w1a[DEA][4], w2c0[4], w2c1[4], b1v[4];
    #pragma unroll
    for (int d = 0; d < DEA; d++) {
        float4 v = *(const float4*)&We1[(2 * HH + d) * HH + lane16 * 4];
        w1a[d][0] = v.x; w1a[d][1] = v.y; w1a[d][2] = v.z; w1a[d][3] = v.w;
    }
    float4 bv = *(const float4*)&be1[lane16 * 4];
    b1v[0] = bv.x; b1v[1] = bv.y; b1v[2] = bv.z; b1v[3] = bv.w;
    #pragma unroll
    for (int j = 0; j < 4; j++) {
        w2c0[j] = We2[(lane16 * 4 + j) * NCLS + 0];
        w2c1[j] = We2[(lane16 * 4 + j) * NCLS + 1];
    }
    float be20 = be2[0], be21 = be2[1];

    int stride = gridDim.x * 64;   // 64 edges per block-iteration; EE%64==0
    for (int e = blockIdx.x * 64 + wave * 16 + grp * 4; e < EE; e += stride) {
        int sv[4], dv[4];
        #pragma unroll
        for (int q = 0; q < 4; q++) { sv[q] = src[e + q]; dv[q] = dst[e + q]; }
        uint2 us[4], ud[4];
        uint4 ua[4];
        float4 at0[4], at1[4];
        #pragma unroll
        for (int q = 0; q < 4; q++) {
            us[q] = *(const uint2*)&p_src[(size_t)sv[q] * HH + lane16 * 4];
            ud[q] = *(const uint2*)&p_dst[(size_t)dv[q] * HH + lane16 * 4];
            if constexpr (A16) {
                ua[q] = *(const uint4*)&attr16[(size_t)(e + q) * DEA];
            } else {
                at0[q] = *(const float4*)&edge_attr[(size_t)(e + q) * DEA];
                at1[q] = *(const float4*)&edge_attr[(size_t)(e + q) * DEA + 4];
            }
        }
        float l0[4], l1[4];
        #pragma unroll
        for (int q = 0; q < 4; q++) {
            float s0, s1, s2, s3, d0, d1, d2, d3;
            bf2x(us[q].x, s0, s1); bf2x(us[q].y, s2, s3);
            bf2x(ud[q].x, d0, d1); bf2x(ud[q].y, d2, d3);
            float t[4] = {s0 + d0 + b1v[0], s1 + d1 + b1v[1],
                          s2 + d2 + b1v[2], s3 + d3 + b1v[3]};
            float av[DEA];
            if constexpr (A16) {
                bf2x(ua[q].x, av[0], av[1]); bf2x(ua[q].y, av[2], av[3]);
                bf2x(ua[q].z, av[4], av[5]); bf2x(ua[q].w, av[6], av[7]);
            } else {
                av[0] = at0[q].x; av[1] = at0[q].y; av[2] = at0[q].z; av[3] = at0[q].w;
                av[4] = at1[q].x; av[5] = at1[q].y; av[6] = at1[q].z; av[7] = at1[q].w;
            }
            l0[q] = 0.f; l1[q] = 0.f;
            #pragma unroll
            for (int j = 0; j < 4; j++) {
                #pragma unroll
                for (int d = 0; d < DEA; d++) t[j] = fmaf(av[d], w1a[d][j], t[j]);
                float r = fmaxf(t[j], 0.f);
                l0[q] = fmaf(r, w2c0[j], l0[q]);
                l1[q] = fmaf(r, w2c1[j], l1[q]);
            }
        }
        #pragma unroll
        for (int off = 8; off; off >>= 1)
            #pragma unroll
            for (int q = 0; q < 4; q++) {
                l0[q] += __shfl_xor(l0[q], off);
                l1[q] += __shfl_xor(l1[q], off);
            }
        if (lane16 == 0) {
            #pragma unroll
            for (int q = 0; q < 4; q++)
                *(float2*)&out_edge[(size_t)(e + q) * NCLS] =
                    make_float2(l0[q] + be20, l1[q] + be21);
        }
    }
}

extern "C" void kernel_launch(void* const* d_in, const int* in_sizes, int n_in,
                              void* d_out, int out_size, void* d_ws, size_t ws_size,
                              hipStream_t stream) {
    const float* x      = (const float*)d_in[0];
    const int*   ei     = (const int*)  d_in[1];
    const float* attr   = (const float*)d_in[2];
    const float* W_enc  = (const float*)d_in[3];
    const float* b_enc  = (const float*)d_in[4];
    const float* W_gat  = (const float*)d_in[5];
    const float* a_src  = (const float*)d_in[6];
    const float* a_dst  = (const float*)d_in[7];
    const float* Wn1    = (const float*)d_in[8];
    const float* bn1    = (const float*)d_in[9];
    const float* Wn2    = (const float*)d_in[10];
    const float* bn2    = (const float*)d_in[11];
    const float* We1    = (const float*)d_in[12];
    const float* be1    = (const float*)d_in[13];
    const float* We2    = (const float*)d_in[14];
    const float* be2    = (const float*)d_in[15];
    float* out = (float*)d_out;
    float* ws  = (float*)d_ws;

    // workspace layout (float units), ~72.2 MB (fit in R13-R15):
    bf16*     hg_psrc = (bf16*)ws;                        // [N*H] bf16: hg, later p_src
    bf16*     agg     = (bf16*)(ws + (size_t)NN * 32);    // [N*H] bf16
    bf16*     p_dst   = (bf16*)(ws + (size_t)NN * 64);    // [N*H] bf16
    float*    ssrc    = ws + (size_t)NN * 96;             // [N]
    float*    sdst    = ssrc + NN;                        // [N]
    int*      bcur    = (int*)(sdst + NN);                // [NBUCK] count cursors
    unsigned* ebuf    = (unsigned*)(bcur + 1024);         // [NBUCK*CAPG] bucket windows
    short*    attr16  = (short*)(ebuf + (size_t)NBUCK * CAPG);  // [E*DEA] bf16 (optional)
    size_t    need    = (size_t)((char*)(attr16 + (size_t)EE * DEA) - (char*)ws);
    bool      a16     = ws_size >= need;                  // deterministic per-session

    const int* srcp = ei;
    const int* dstp = ei + EE;

    hipMemsetAsync(bcur, 0, NBUCK * sizeof(int), stream);
    int front_blocks = NENC + NCHUNK + (a16 ? NCVT : 0);
    k_front   <<<front_blocks, 512, 0, stream>>>(x, W_enc, b_enc, W_gat, a_src, a_dst,
                                                 hg_psrc, ssrc, sdst,
                                                 srcp, dstp, bcur, ebuf,
                                                 attr, a16 ? attr16 : nullptr);
    k_bagg2   <<<NBUCK, 512, 0, stream>>>(ebuf, bcur, ssrc, sdst, hg_psrc, agg);
    k_nodehead<<<782, 256, 0, stream>>>(agg, Wn1, bn1, Wn2, bn2, We1,
                                        hg_psrc /*p_src*/, p_dst, out);
    if (a16)
        k_edgehead<true><<<8192, 256, 0, stream>>>(srcp, dstp, attr, attr16,
                                                   hg_psrc, p_dst, We1, be1, We2, be2,
                                                   out + (size_t)NN * NCLS);
    else
        k_edgehead<false><<<8192, 256, 0, stream>>>(srcp, dstp, attr, nullptr,
                                                    hg_psrc, p_dst, We1, be1, We2, be2,
                                                    out + (size_t)NN * NCLS);
}